// Round 19
// baseline (500.622 us; speedup 1.0000x reference)
//
#include <hip/hip_runtime.h>
#include <math.h>

#define NN 20000
#define NE 200000
#define HH 512

typedef __attribute__((ext_vector_type(8))) short short8v;
typedef __attribute__((ext_vector_type(4))) float f32x4;

__device__ inline short f2bf(float f) {
    union { float f; unsigned u; } v; v.f = f;
    unsigned r = (v.u + 0x7fffu + ((v.u >> 16) & 1u)) >> 16;
    return (short)r;
}
__device__ inline float bf2f(short s) {
    union { unsigned u; float f; } v;
    v.u = ((unsigned)(unsigned short)s) << 16;
    return v.f;
}

__device__ inline void gload_lds16(const void* g, void* l) {
    __builtin_amdgcn_global_load_lds(
        (const __attribute__((address_space(1))) void*)g,
        (__attribute__((address_space(3))) void*)l, 16, 0, 0);
}

// ---------------- batched weight transpose+bf16 (+ z=9: plain Wu convert) ---
__global__ __launch_bounds__(256)
void wtr_all(const float* __restrict__ Wu, const float* __restrict__ Wi,
             const float* __restrict__ gfW, const float* __restrict__ prW,
             const float* __restrict__ dW,
             short* __restrict__ WTu, short* __restrict__ WTi,
             short* __restrict__ WTg0, short* __restrict__ WTg1,
             short* __restrict__ WTpr, short* __restrict__ WTd,
             short* __restrict__ WuB)
{
    __shared__ float t[32][33];
    int z = blockIdx.z;
    int by = blockIdx.y * 32;
    int bx = blockIdx.x * 32;
    int tx = threadIdx.x, ty = threadIdx.y;
    if (z == 9) {
        for (int i = ty; i < 32; i += 8)
            WuB[(size_t)(by + i) * 512 + bx + tx] =
                f2bf(Wu[(size_t)(by + i) * 512 + bx + tx]);
        return;
    }
    const float* src; short* dst; int K;
    if (z == 0)      { src = Wu;  dst = WTu;  K = 512; }
    else if (z == 1) { src = Wi;  dst = WTi;  K = 256; }
    else if (z == 2) { src = gfW; dst = WTg0; K = 512; }
    else if (z == 3) { src = gfW + (size_t)512 * 512; dst = WTg1; K = 512; }
    else if (z == 4) { src = prW; dst = WTpr; K = 512; }
    else { src = dW + (size_t)(z - 5) * 512 * 512;
           dst = WTd + (size_t)(z - 5) * 512 * 512; K = 512; }
    if (by >= K) return;
    for (int i = ty; i < 32; i += 8)
        t[i][tx] = src[(size_t)(by + i) * 512 + bx + tx];
    __syncthreads();
    for (int i = ty; i < 32; i += 8)
        dst[(size_t)(bx + i) * K + by + tx] = f2bf(t[tx][i]);
}

// ---------------- MFMA GEMM (128x128, BK=64, 2-stage counted vmcnt) ---------
// bf16 A; nullable bias; optional MIXED rowdot tail:
// ss = fp32 rdF(512)·rdfv + rdc[0] ; ts = bf16 rdB(512)·rdbv + rdc[1]
__global__ __launch_bounds__(256)
void mfma_lin(const short* __restrict__ X, const short* __restrict__ WT,
              const float* __restrict__ bias, float* __restrict__ outF,
              short* __restrict__ outB, int M, int K,
              const float* __restrict__ rdF, const float* __restrict__ rdfv,
              const short* __restrict__ rdB, const float* __restrict__ rdbv,
              const float* __restrict__ rdc, float* __restrict__ rdss,
              float* __restrict__ rdts, int rdN)
{
    __shared__ short8v pool[4096];   // 64 KB

    const int tid = threadIdx.x;
    const int lane = tid & 63;
    const int w = tid >> 6;

    const int nby = (M + 127) >> 7;
    const int nwg = nby << 2;
    int id = blockIdx.x;

    if (id >= nwg) {                 // ---------- mixed rowdot role ----------
        int row = (id - nwg) * 4 + w;
        if (!rdF || row >= rdN) return;
        const float4* fp = (const float4*)(rdF + (size_t)row * HH) + lane * 2;
        float4 f0 = fp[0], f1 = fp[1];
        const float4* up = (const float4*)rdfv + lane * 2;
        float4 u0 = up[0], u1 = up[1];
        float a = f0.x*u0.x + f0.y*u0.y + f0.z*u0.z + f0.w*u0.w
                + f1.x*u1.x + f1.y*u1.y + f1.z*u1.z + f1.w*u1.w;
        short8v t = ((const short8v*)(rdB + (size_t)row * HH))[lane];
        const float4* vp = (const float4*)rdbv + lane * 2;
        float4 v0 = vp[0], v1 = vp[1];
        float b = bf2f(t[0])*v0.x + bf2f(t[1])*v0.y + bf2f(t[2])*v0.z + bf2f(t[3])*v0.w
                + bf2f(t[4])*v1.x + bf2f(t[5])*v1.y + bf2f(t[6])*v1.z + bf2f(t[7])*v1.w;
#pragma unroll
        for (int m = 32; m >= 1; m >>= 1) {
            a += __shfl_xor(a, m);
            b += __shfl_xor(b, m);
        }
        if (lane == 0) { rdss[row] = a + rdc[0]; rdts[row] = b + rdc[1]; }
        return;
    }

    // ---------- GEMM role ----------
    const int q = nwg >> 3, r = nwg & 7;
    int xcd = id & 7, wi = id >> 3;
    int wgid = (xcd < r ? xcd * (q + 1) : r * (q + 1) + (xcd - r) * q) + wi;
    const int col0 = (wgid & 3) * 128;
    const int row0 = (wgid >> 2) * 128;

    const int wr = (w >> 1) * 64;
    const int wc = (w & 1) * 64;

    const short* gsrc[8];
#pragma unroll
    for (int g = 0; g < 8; ++g) {
        int p = w * 512 + g * 64 + lane;
        if (p < 1024) {
            int row = p >> 3;
            int c = (p & 7) ^ (row & 7);
            int ga = row0 + row; if (ga >= M) ga = M - 1;
            gsrc[g] = X + (size_t)ga * K + c * 8;
        } else {
            int qq = p - 1024;
            int col = qq >> 3;
            int c = (qq & 7) ^ (col & 7);
            gsrc[g] = WT + (size_t)(col0 + col) * K + c * 8;
        }
    }

    int ar[2][4], br[2][4];
#pragma unroll
    for (int kk = 0; kk < 2; ++kk) {
#pragma unroll
        for (int i = 0; i < 4; ++i) {
            int rr = wr + i * 16 + (lane & 15);
            ar[kk][i] = rr * 8 + ((kk * 4 + (lane >> 4)) ^ (rr & 7));
            int nn = wc + i * 16 + (lane & 15);
            br[kk][i] = 1024 + nn * 8 + ((kk * 4 + (lane >> 4)) ^ (nn & 7));
        }
    }

    f32x4 acc[4][4];
#pragma unroll
    for (int i = 0; i < 4; ++i)
#pragma unroll
        for (int j = 0; j < 4; ++j)
            acc[i][j] = (f32x4){0.f, 0.f, 0.f, 0.f};

    auto stage = [&](int buf, int kk) {
        short8v* base = pool + buf * 2048 + w * 512;
#pragma unroll
        for (int g = 0; g < 8; ++g)
            gload_lds16(gsrc[g] + kk, base + g * 64);
    };

    const int nt = K >> 6;
    stage(0, 0);
    if (nt > 1) stage(1, 64);
    int cur = 0;
    for (int t = 0; t < nt; ++t) {
        if (t + 1 < nt) asm volatile("s_waitcnt vmcnt(8)" ::: "memory");
        else            asm volatile("s_waitcnt vmcnt(0)" ::: "memory");
        __builtin_amdgcn_s_barrier();
        const short8v* S = pool + cur * 2048;
#pragma unroll
        for (int kk = 0; kk < 2; ++kk) {
            short8v af[4], bf[4];
#pragma unroll
            for (int i = 0; i < 4; ++i) af[i] = S[ar[kk][i]];
#pragma unroll
            for (int j = 0; j < 4; ++j) bf[j] = S[br[kk][j]];
#pragma unroll
            for (int i = 0; i < 4; ++i)
#pragma unroll
                for (int j = 0; j < 4; ++j)
                    acc[i][j] = __builtin_amdgcn_mfma_f32_16x16x32_bf16(af[i], bf[j], acc[i][j], 0, 0, 0);
        }
        __builtin_amdgcn_s_barrier();
        if (t + 2 < nt) stage(cur, (t + 2) * 64);
        cur ^= 1;
    }

    float bj[4];
#pragma unroll
    for (int j = 0; j < 4; ++j)
        bj[j] = bias ? bias[col0 + wc + j * 16 + (lane & 15)] : 0.f;

    if (outF) {
#pragma unroll
        for (int i = 0; i < 4; ++i) {
#pragma unroll
            for (int rr = 0; rr < 4; ++rr) {
                int row = row0 + wr + i * 16 + (lane >> 4) * 4 + rr;
                if (row < M) {
                    float* op = outF + (size_t)row * HH + col0 + wc + (lane & 15);
#pragma unroll
                    for (int j = 0; j < 4; ++j) op[j * 16] = acc[i][j][rr] + bj[j];
                }
            }
        }
    }
    if (outB) {
        short* lt = (short*)pool;    // [128][136] bf16
#pragma unroll
        for (int i = 0; i < 4; ++i)
#pragma unroll
            for (int rr = 0; rr < 4; ++rr) {
                int lrow = wr + i * 16 + (lane >> 4) * 4 + rr;
#pragma unroll
                for (int j = 0; j < 4; ++j)
                    lt[lrow * 136 + wc + j * 16 + (lane & 15)] = f2bf(acc[i][j][rr] + bj[j]);
            }
        __syncthreads();
#pragma unroll
        for (int k = 0; k < 8; ++k) {
            int row = (tid >> 4) + 16 * k;
            int seg = tid & 15;
            int grow = row0 + row;
            if (grow < M) {
                short8v vv = *(short8v*)(lt + row * 136 + seg * 8);
                *(short8v*)(outB + (size_t)grow * HH + col0 + seg * 8) = vv;
            }
        }
    }
}

// ---------------- mfma_multi: 3 independent fp32-A GEMMs + GAT1 rowdot ------
// Early-issue A pipeline: A(T+2) issued right after conversion frees the reg
// set (start of body T) -> ~2-body prefetch distance vs HBM latency.
__global__ __launch_bounds__(256)
void mfma_multi(const float* __restrict__ A0, const short* __restrict__ W0,
                const float* __restrict__ b0, short* __restrict__ O0,
                const float* __restrict__ A1, const short* __restrict__ W1,
                const float* __restrict__ b1, short* __restrict__ O1,
                const float* __restrict__ A2, const short* __restrict__ W2,
                const float* __restrict__ b2, short* __restrict__ O2,
                int M,
                const float* __restrict__ rdF1, const float* __restrict__ rdv1,
                const float* __restrict__ rdF2, const float* __restrict__ rdv2,
                const float* __restrict__ rdc, float* __restrict__ rdss,
                float* __restrict__ rdts, int rdN)
{
    __shared__ short8v pool[2304];   // 36 KB

    const int tid = threadIdx.x;
    const int lane = tid & 63;
    const int w = tid >> 6;

    const int nby = (M + 127) >> 7;
    const int nwg = nby << 2;
    int id = blockIdx.x;

    if (id >= 3 * nwg) {             // ---------- GAT1 rowdot (raw inputs) ----
        int row = (id - 3 * nwg) * 4 + w;
        if (row >= rdN) return;
        const float4* fp = (const float4*)(rdF1 + (size_t)row * 256) + lane;
        float4 f = fp[0];
        const float4* u1p = (const float4*)rdv1 + lane;
        float4 u1 = u1p[0];
        float a = f.x*u1.x + f.y*u1.y + f.z*u1.z + f.w*u1.w;
        const float4* tp = (const float4*)(rdF2 + (size_t)row * HH) + lane * 2;
        float4 t0v = tp[0], t1v = tp[1];
        const float4* vp = (const float4*)rdv2 + lane * 2;
        float4 v0 = vp[0], v1 = vp[1];
        float b = t0v.x*v0.x + t0v.y*v0.y + t0v.z*v0.z + t0v.w*v0.w
                + t1v.x*v1.x + t1v.y*v1.y + t1v.z*v1.z + t1v.w*v1.w;
#pragma unroll
        for (int m = 32; m >= 1; m >>= 1) {
            a += __shfl_xor(a, m);
            b += __shfl_xor(b, m);
        }
        if (lane == 0) { rdss[row] = a + rdc[0]; rdts[row] = b + rdc[1]; }
        return;
    }

    // ---------- GEMM role, segment select ----------
    int seg = id / nwg;
    int sid = id - seg * nwg;
    const float* XA = (seg == 0) ? A0 : ((seg == 1) ? A1 : A2);
    const short* WT = (seg == 0) ? W0 : ((seg == 1) ? W1 : W2);
    const float* bias = (seg == 0) ? b0 : ((seg == 1) ? b1 : b2);
    short* outB = (seg == 0) ? O0 : ((seg == 1) ? O1 : O2);
    const int K = (seg == 1) ? 256 : 512;

    const int q = nwg >> 3, r = nwg & 7;
    int xcd = sid & 7, wi = sid >> 3;
    int wgid = (xcd < r ? xcd * (q + 1) : r * (q + 1) + (xcd - r) * q) + wi;
    const int col0 = (wgid & 3) * 128;
    const int row0 = (wgid >> 2) * 128;

    const int wr = (w >> 1) * 64;
    const int wc = (w & 1) * 64;

    const int srow = tid >> 1;
    const int sc0 = (tid & 1) * 2;
    int garow = row0 + srow; if (garow >= M) garow = M - 1;
    const float* abase = XA + (size_t)garow * K + sc0 * 8;
    const int aswz = (srow >> 1) & 3;
    const int wi0 = srow * 4 + (sc0 ^ aswz);
    const int wi1 = srow * 4 + ((sc0 + 1) ^ aswz);

    const short* bsrc0; const short* bsrc1;
    int bbase0, bbase1;
    {
        int p0 = w * 128 + lane;
        int col = p0 >> 2;
        int c = (p0 & 3) ^ ((col >> 1) & 3);
        bsrc0 = WT + (size_t)(col0 + col) * K + c * 8;
        bbase0 = w * 128;
        int p1 = w * 128 + 64 + lane;
        col = p1 >> 2;
        c = (p1 & 3) ^ ((col >> 1) & 3);
        bsrc1 = WT + (size_t)(col0 + col) * K + c * 8;
        bbase1 = w * 128 + 64;
    }

    int ar[4], br[4];
#pragma unroll
    for (int i = 0; i < 4; ++i) {
        int rr = wr + i * 16 + (lane & 15);
        ar[i] = rr * 4 + ((lane >> 4) ^ ((rr >> 1) & 3));
        int nn = wc + i * 16 + (lane & 15);
        br[i] = 512 + nn * 4 + ((lane >> 4) ^ ((nn >> 1) & 3));
    }

    f32x4 acc[4][4];
#pragma unroll
    for (int i = 0; i < 4; ++i)
#pragma unroll
        for (int j = 0; j < 4; ++j)
            acc[i][j] = (f32x4){0.f, 0.f, 0.f, 0.f};

    const int nt = K >> 5;            // 16 or 8 (even)
    float4 rA0[4], rA1[4];

#define ISSUE_A(RA, T) {                                                   \
        const float4* p_ = (const float4*)(abase + (T) * 32);              \
        RA[0] = p_[0]; RA[1] = p_[1]; RA[2] = p_[2]; RA[3] = p_[3]; }
#define ISSUE_B(BUF, T) {                                                  \
        short8v* bb_ = pool + (BUF) * 1024 + 512;                          \
        gload_lds16(bsrc0 + (T) * 32, bb_ + bbase0);                       \
        gload_lds16(bsrc1 + (T) * 32, bb_ + bbase1); }
#define LINF_BODY(BUF, RA, T) {                                            \
        short8v s0_, s1_;                                                  \
        s0_[0]=f2bf(RA[0].x); s0_[1]=f2bf(RA[0].y); s0_[2]=f2bf(RA[0].z); s0_[3]=f2bf(RA[0].w); \
        s0_[4]=f2bf(RA[1].x); s0_[5]=f2bf(RA[1].y); s0_[6]=f2bf(RA[1].z); s0_[7]=f2bf(RA[1].w); \
        s1_[0]=f2bf(RA[2].x); s1_[1]=f2bf(RA[2].y); s1_[2]=f2bf(RA[2].z); s1_[3]=f2bf(RA[2].w); \
        s1_[4]=f2bf(RA[3].x); s1_[5]=f2bf(RA[3].y); s1_[6]=f2bf(RA[3].z); s1_[7]=f2bf(RA[3].w); \
        short8v* A_ = pool + (BUF) * 1024;                                 \
        A_[wi0] = s0_; A_[wi1] = s1_;                                      \
        if ((T) + 2 < nt) ISSUE_A(RA, (T) + 2);   /* early re-issue */     \
        if ((T) + 2 < nt)      asm volatile("s_waitcnt vmcnt(10) lgkmcnt(0)" ::: "memory"); \
        else if ((T) + 1 < nt) asm volatile("s_waitcnt vmcnt(6) lgkmcnt(0)" ::: "memory"); \
        else                   asm volatile("s_waitcnt vmcnt(0) lgkmcnt(0)" ::: "memory"); \
        __builtin_amdgcn_s_barrier();                                      \
        const short8v* S_ = pool + (BUF) * 1024;                           \
        short8v af_[4], bf_[4];                                            \
        _Pragma("unroll")                                                  \
        for (int i_ = 0; i_ < 4; ++i_) af_[i_] = S_[ar[i_]];               \
        _Pragma("unroll")                                                  \
        for (int j_ = 0; j_ < 4; ++j_) bf_[j_] = S_[br[j_]];               \
        _Pragma("unroll")                                                  \
        for (int i_ = 0; i_ < 4; ++i_)                                     \
            _Pragma("unroll")                                              \
            for (int j_ = 0; j_ < 4; ++j_)                                 \
                acc[i_][j_] = __builtin_amdgcn_mfma_f32_16x16x32_bf16(af_[i_], bf_[j_], acc[i_][j_], 0, 0, 0); \
        __builtin_amdgcn_s_barrier();                                      \
        if ((T) + 2 < nt) { ISSUE_B(BUF, (T) + 2); } }

    ISSUE_A(rA0, 0);
    ISSUE_B(0, 0);
    ISSUE_A(rA1, 1);
    ISSUE_B(1, 1);
    for (int t = 0; t < nt; t += 2) {
        LINF_BODY(0, rA0, t);
        LINF_BODY(1, rA1, t + 1);
    }
#undef ISSUE_A
#undef ISSUE_B
#undef LINF_BODY

    float bj[4];
#pragma unroll
    for (int j = 0; j < 4; ++j)
        bj[j] = bias[col0 + wc + j * 16 + (lane & 15)];

    short* lt = (short*)pool;
#pragma unroll
    for (int i = 0; i < 4; ++i)
#pragma unroll
        for (int rr = 0; rr < 4; ++rr) {
            int lrow = wr + i * 16 + (lane >> 4) * 4 + rr;
#pragma unroll
            for (int j = 0; j < 4; ++j)
                lt[lrow * 136 + wc + j * 16 + (lane & 15)] = f2bf(acc[i][j][rr] + bj[j]);
        }
    __syncthreads();
#pragma unroll
    for (int k = 0; k < 8; ++k) {
        int row = (tid >> 4) + 16 * k;
        int seg2 = tid & 15;
        int grow = row0 + row;
        if (grow < M) {
            short8v vv = *(short8v*)(lt + row * 136 + seg2 * 8);
            *(short8v*)(outB + (size_t)grow * HH + col0 + seg2 * 8) = vv;
        }
    }
}

// ---------------- gat_pre for BOTH relations (one launch) -------------------
__global__ __launch_bounds__(256)
void gat_pre2(const float* __restrict__ gfW, const float* __restrict__ gfb,
              const float* __restrict__ gaw, float* __restrict__ uvall,
              float* __restrict__ s0t0all)
{
    int rrel = blockIdx.y;
    const float* fW = gfW + (size_t)rrel * HH * HH;
    const float* fb = gfb + rrel * HH;
    const float* aw = gaw + (size_t)rrel * 2 * HH;
    float* uv = uvall + rrel * 1024;
    float* s0t0 = s0t0all + rrel * 4;
    int row = blockIdx.x * 4 + (threadIdx.x >> 6);
    int lane = threadIdx.x & 63;
    const float4* ah = (const float4*)aw;
    const float4* at = (const float4*)(aw + HH);
    const float4* fp;
    if (row < 512)       fp = (const float4*)(fW + (size_t)row * HH);
    else if (row == 512) fp = (const float4*)fb;
    else return;
    float du = 0.f, dv = 0.f;
#pragma unroll
    for (int l = 0; l < 2; ++l) {
        int idx = lane * 2 + l;
        float4 f = fp[idx], a = ah[idx], b = at[idx];
        du += f.x*a.x + f.y*a.y + f.z*a.z + f.w*a.w;
        dv += f.x*b.x + f.y*b.y + f.z*b.z + f.w*b.w;
    }
#pragma unroll
    for (int m = 32; m >= 1; m >>= 1) {
        du += __shfl_xor(du, m);
        dv += __shfl_xor(dv, m);
    }
    if (lane == 0) {
        if (row < 512) { uv[row] = du; uv[512 + row] = dv; }
        else           { s0t0[0] = du; s0t0[1] = dv; }
    }
}

// ---------------- wuvbc2: composition vectors for both GATs ----------------
__global__ __launch_bounds__(256)
void wuvbc2_kernel(const float* __restrict__ Wu, const float* __restrict__ bu,
                   const float* __restrict__ Wi, const float* __restrict__ bi,
                   const short* __restrict__ WTg1, const float* __restrict__ fb1,
                   const float* __restrict__ uvall, const float* __restrict__ s0t0a,
                   float* __restrict__ wuv, float* __restrict__ cpair1,
                   float* __restrict__ bcomp, float* __restrict__ wiu,
                   float* __restrict__ wuu0, float* __restrict__ cpair0)
{
    int row = blockIdx.x * 4 + (threadIdx.x >> 6);
    int lane = threadIdx.x & 63;
    int y = blockIdx.y;
    if (y == 0 || y == 3) {
        const float* vec = (y == 0) ? (uvall + 1024 + 512) : (uvall + 0);
        const float4* vp = (const float4*)vec + lane * 2;
        float4 v0 = vp[0], v1v = vp[1];
        const float4* fp;
        if (row < 512)       fp = (const float4*)(Wu + (size_t)row * HH);
        else if (row == 512) fp = (const float4*)bu;
        else return;
        const float4* p = fp + lane * 2;
        float4 a = p[0], b = p[1];
        float d = a.x*v0.x + a.y*v0.y + a.z*v0.z + a.w*v0.w
                + b.x*v1v.x + b.y*v1v.y + b.z*v1v.z + b.w*v1v.w;
#pragma unroll
        for (int m = 32; m >= 1; m >>= 1) d += __shfl_xor(d, m);
        if (lane == 0) {
            if (y == 0) {
                if (row < 512) wuv[row] = d;
                else           cpair1[1] = d + s0t0a[5];
            } else {
                if (row < 512) wuu0[row] = d;
                else { cpair0[0] = d + s0t0a[0]; cpair0[1] = s0t0a[1]; }
            }
        }
    } else if (y == 1) {
        if (row >= 512) return;
        short8v wv8 = ((const short8v*)(WTg1 + (size_t)row * HH))[lane];
        const float4* bp = (const float4*)bu + lane * 2;
        float4 b0 = bp[0], b1 = bp[1];
        float d = bf2f(wv8[0])*b0.x + bf2f(wv8[1])*b0.y + bf2f(wv8[2])*b0.z + bf2f(wv8[3])*b0.w
                + bf2f(wv8[4])*b1.x + bf2f(wv8[5])*b1.y + bf2f(wv8[6])*b1.z + bf2f(wv8[7])*b1.w;
#pragma unroll
        for (int m = 32; m >= 1; m >>= 1) d += __shfl_xor(d, m);
        if (lane == 0) bcomp[row] = d + fb1[row];
    } else {   // y == 2
        const float* u1 = uvall + 1024;
        const float4* vp = (const float4*)u1 + lane * 2;
        float4 v0 = vp[0], v1v = vp[1];
        const float4* fp;
        if (row < 256)       fp = (const float4*)(Wi + (size_t)row * HH);
        else if (row == 256) fp = (const float4*)bi;
        else return;
        const float4* p = fp + lane * 2;
        float4 a = p[0], b = p[1];
        float d = a.x*v0.x + a.y*v0.y + a.z*v0.z + a.w*v0.w
                + b.x*v1v.x + b.y*v1v.y + b.z*v1v.z + b.w*v1v.w;
#pragma unroll
        for (int m = 32; m >= 1; m >>= 1) d += __shfl_xor(d, m);
        if (lane == 0) {
            if (row < 256) wiu[row] = d;
            else           cpair1[0] = d + s0t0a[4];
        }
    }
}

// ---------------- CSR build ----------------
__global__ __launch_bounds__(256)
void count2_kernel(const int* __restrict__ s0, const int* __restrict__ s1,
                   int* __restrict__ c0, int* __restrict__ c1, int E)
{
    int i = blockIdx.x * blockDim.x + threadIdx.x;
    if (i < E) atomicAdd(&c0[s0[i]], 1);
    else if (i < 2 * E) atomicAdd(&c1[s1[i - E]], 1);
}

__global__ __launch_bounds__(1024)
void scan2_kernel(const int* __restrict__ c0, const int* __restrict__ c1,
                  int* __restrict__ o0, int* __restrict__ o1,
                  int* __restrict__ u0, int* __restrict__ u1, int n)
{
    const int* counts = blockIdx.x ? c1 : c0;
    int* offs = blockIdx.x ? o1 : o0;
    int* curs = blockIdx.x ? u1 : u0;
    __shared__ int part[1024];
    const int tid = threadIdx.x;
    const int CH = (n + 1023) / 1024;
    const int base = tid * CH;
    int s = 0;
    for (int i = 0; i < CH; ++i) {
        int idx = base + i;
        if (idx < n) s += counts[idx];
    }
    part[tid] = s;
    __syncthreads();
    for (int d = 1; d < 1024; d <<= 1) {
        int v = 0;
        if (tid >= d) v = part[tid - d];
        __syncthreads();
        if (tid >= d) part[tid] += v;
        __syncthreads();
    }
    int run = (tid == 0) ? 0 : part[tid - 1];
    for (int i = 0; i < CH; ++i) {
        int idx = base + i;
        if (idx < n) { offs[idx] = run; curs[idx] = run; run += counts[idx]; }
    }
    if (tid == 1023) offs[n] = run;
}

__global__ __launch_bounds__(256)
void fill_kernel(const int* __restrict__ src, const int* __restrict__ tgt,
                 const float* __restrict__ ss, const float* __restrict__ ts,
                 const float* __restrict__ ab_ptr, int* __restrict__ cursor,
                 int* __restrict__ tvals, float* __restrict__ wv,
                 int* __restrict__ eidx, int E)
{
    int i = blockIdx.x * blockDim.x + threadIdx.x;
    if (i >= E) return;
    int s = src[i], t = tgt[i];
    int pos = atomicAdd(&cursor[s], 1);
    tvals[pos] = t;
    wv[pos] = expf(tanhf(ss[s] + ts[t] + ab_ptr[0]));
    eidx[pos] = i;
}

// ---------------- fused GAT: in-wave canonical sort + aggregate + combine ---
__global__ __launch_bounds__(256)
void gat_agg_kernel(const int* __restrict__ offs, const int* __restrict__ tvals,
                    const float* __restrict__ wv, const int* __restrict__ eidx,
                    const short* __restrict__ T, const short* __restrict__ head,
                    const float* __restrict__ gbias, short* __restrict__ out, int N)
{
    __shared__ int   slt[4][512];
    __shared__ float slw[4][512];
    int w = threadIdx.x >> 6;
    int lane = threadIdx.x & 63;
    int s = blockIdx.x * 4 + w;
    if (s >= N) return;
    const int beg = offs[s], end = offs[s + 1];
    int L = end - beg;
    if (L > 512) L = 512;

    if (L <= 64) {
        int e = 0x7fffffff, t = 0; float fw = 0.f;
        if (lane < L) { e = eidx[beg + lane]; t = tvals[beg + lane]; fw = wv[beg + lane]; }
        int r = 0;
        for (int k = 0; k < L; ++k)
            r += (__shfl(e, k) < e) ? 1 : 0;
        if (lane < L) { slt[w][r] = t; slw[w][r] = fw; }
    } else {
        for (int j = lane; j < L; j += 64) {
            int e = eidx[beg + j];
            int r = 0;
            for (int k = 0; k < L; ++k) r += (eidx[beg + k] < e) ? 1 : 0;
            slt[w][r] = tvals[beg + j]; slw[w][r] = wv[beg + j];
        }
    }
    asm volatile("s_waitcnt lgkmcnt(0)" ::: "memory");

    float a[8];
#pragma unroll
    for (int q = 0; q < 8; ++q) a[q] = 0.f;
    float den = 0.f;

    int j = 0;
    for (; j + 8 <= L; j += 8) {
        short8v v[8];
        float wgt[8];
#pragma unroll
        for (int u = 0; u < 8; ++u) {
            wgt[u] = slw[w][j + u];
            v[u] = ((const short8v*)(T + (size_t)slt[w][j + u] * HH))[lane];
        }
#pragma unroll
        for (int u = 0; u < 8; ++u) {
            den += wgt[u];
#pragma unroll
            for (int q = 0; q < 8; ++q) a[q] = fmaf(wgt[u], bf2f(v[u][q]), a[q]);
        }
    }
    for (; j + 4 <= L; j += 4) {
        short8v v[4];
        float wgt[4];
#pragma unroll
        for (int u = 0; u < 4; ++u) {
            wgt[u] = slw[w][j + u];
            v[u] = ((const short8v*)(T + (size_t)slt[w][j + u] * HH))[lane];
        }
#pragma unroll
        for (int u = 0; u < 4; ++u) {
            den += wgt[u];
#pragma unroll
            for (int q = 0; q < 8; ++q) a[q] = fmaf(wgt[u], bf2f(v[u][q]), a[q]);
        }
    }
    for (; j < L; ++j) {
        float fw = slw[w][j];
        short8v tv = ((const short8v*)(T + (size_t)slt[w][j] * HH))[lane];
        den += fw;
#pragma unroll
        for (int q = 0; q < 8; ++q) a[q] = fmaf(fw, bf2f(tv[q]), a[q]);
    }
    float inv = (den > 0.f) ? 1.f / den : 0.f;

    short8v h = ((const short8v*)(head + (size_t)s * HH))[lane];
    const float4* bp = (const float4*)gbias + lane * 2;
    float4 b0 = bp[0], b1 = bp[1];
    float bb[8] = {b0.x, b0.y, b0.z, b0.w, b1.x, b1.y, b1.z, b1.w};
    short8v o;
#pragma unroll
    for (int q = 0; q < 8; ++q)
        o[q] = f2bf((bf2f(h[q]) + a[q] * inv + bb[q]) * 0.5f);
    ((short8v*)(out + (size_t)s * HH))[lane] = o;
}

// ---------------- single tanh+LN (d=0 layers) -------------------------------
__global__ __launch_bounds__(256)
void tanh_ln_kernel(const short* __restrict__ Z,
                    const float* __restrict__ g, const float* __restrict__ bta,
                    short* __restrict__ outB, int N)
{
    int row = blockIdx.x * 4 + (threadIdx.x >> 6);
    int lane = threadIdx.x & 63;
    if (row >= N) return;
    short8v zv = ((const short8v*)(Z + (size_t)row * HH))[lane];
    float v[8];
    float sum = 0.f, sum2 = 0.f;
#pragma unroll
    for (int q = 0; q < 8; ++q) {
        float t = tanhf(bf2f(zv[q]));
        v[q] = t; sum += t; sum2 = fmaf(t, t, sum2);
    }
#pragma unroll
    for (int m = 32; m >= 1; m >>= 1) {
        sum += __shfl_xor(sum, m); sum2 += __shfl_xor(sum2, m);
    }
    float mu = sum * (1.f/HH);
    float rs = rsqrtf(sum2 * (1.f/HH) - mu*mu + 1e-5f);
    const float4* gp = (const float4*)g + lane * 2;
    const float4* bp = (const float4*)bta + lane * 2;
    float4 g0 = gp[0], g1 = gp[1], c0 = bp[0], c1 = bp[1];
    float gg[8] = {g0.x, g0.y, g0.z, g0.w, g1.x, g1.y, g1.z, g1.w};
    float cc[8] = {c0.x, c0.y, c0.z, c0.w, c1.x, c1.y, c1.z, c1.w};
    short8v ob;
#pragma unroll
    for (int q = 0; q < 8; ++q) ob[q] = f2bf((v[q]-mu)*rs*gg[q] + cc[q]);
    ((short8v*)(outB + (size_t)row * HH))[lane] = ob;
}

// ---------------- fused double LN (d=1 + residual) --------------------------
__global__ __launch_bounds__(256)
void tanh_ln2_kernel(const short* __restrict__ Z, const float* __restrict__ sc,
                     const float* __restrict__ g1, const float* __restrict__ b1,
                     const float* __restrict__ g2, const float* __restrict__ b2,
                     short* __restrict__ outB, float* __restrict__ outF,
                     const float* __restrict__ cWp, const float* __restrict__ cbp,
                     float* __restrict__ outCls, int N)
{
    int row = blockIdx.x * 4 + (threadIdx.x >> 6);
    int lane = threadIdx.x & 63;
    if (row >= N) return;
    short8v zv = ((const short8v*)(Z + (size_t)row * HH))[lane];
    float v[8];
    float sum = 0.f, sum2 = 0.f;
#pragma unroll
    for (int q = 0; q < 8; ++q) {
        float t = tanhf(bf2f(zv[q]));
        v[q] = t; sum += t; sum2 = fmaf(t, t, sum2);
    }
#pragma unroll
    for (int m = 32; m >= 1; m >>= 1) {
        sum += __shfl_xor(sum, m); sum2 += __shfl_xor(sum2, m);
    }
    float mu = sum * (1.f/HH);
    float rs = rsqrtf(sum2 * (1.f/HH) - mu*mu + 1e-5f);
    {
        const float4* gp = (const float4*)g1 + lane * 2;
        const float4* bp = (const float4*)b1 + lane * 2;
        float4 g0 = gp[0], g1v = gp[1], c0 = bp[0], c1 = bp[1];
        float gg[8] = {g0.x, g0.y, g0.z, g0.w, g1v.x, g1v.y, g1v.z, g1v.w};
        float cc[8] = {c0.x, c0.y, c0.z, c0.w, c1.x, c1.y, c1.z, c1.w};
        const float4* sp = (const float4*)(sc + (size_t)row * HH) + lane * 2;
        float4 s0 = sp[0], s1 = sp[1];
        float ssv[8] = {s0.x, s0.y, s0.z, s0.w, s1.x, s1.y, s1.z, s1.w};
        sum = 0.f; sum2 = 0.f;
#pragma unroll
        for (int q = 0; q < 8; ++q) {
            float x2 = (v[q]-mu)*rs*gg[q] + cc[q];
            float t = tanhf(ssv[q] + x2);
            v[q] = t; sum += t; sum2 = fmaf(t, t, sum2);
        }
    }
#pragma unroll
    for (int m = 32; m >= 1; m >>= 1) {
        sum += __shfl_xor(sum, m); sum2 += __shfl_xor(sum2, m);
    }
    mu = sum * (1.f/HH);
    rs = rsqrtf(sum2 * (1.f/HH) - mu*mu + 1e-5f);
    const float4* gp = (const float4*)g2 + lane * 2;
    const float4* bp = (const float4*)b2 + lane * 2;
    float4 g0 = gp[0], g1v = gp[1], c0 = bp[0], c1 = bp[1];
    float gg[8] = {g0.x, g0.y, g0.z, g0.w, g1v.x, g1v.y, g1v.z, g1v.w};
    float cc[8] = {c0.x, c0.y, c0.z, c0.w, c1.x, c1.y, c1.z, c1.w};
    float o[8];
#pragma unroll
    for (int q = 0; q < 8; ++q) o[q] = (v[q]-mu)*rs*gg[q] + cc[q];
    if (outB) {
        short8v ob;
#pragma unroll
        for (int q = 0; q < 8; ++q) ob[q] = f2bf(o[q]);
        ((short8v*)(outB + (size_t)row * HH))[lane] = ob;
    }
    if (outF) {
        float4* op = (float4*)(outF + (size_t)row * HH) + lane * 2;
        op[0] = make_float4(o[0], o[1], o[2], o[3]);
        op[1] = make_float4(o[4], o[5], o[6], o[7]);
    }
    if (cWp) {
        const float4* wp = (const float4*)cWp + lane * 2;
        float4 w0 = wp[0], w1 = wp[1];
        float acc = o[0]*w0.x + o[1]*w0.y + o[2]*w0.z + o[3]*w0.w
                  + o[4]*w1.x + o[5]*w1.y + o[6]*w1.z + o[7]*w1.w;
#pragma unroll
        for (int m = 32; m >= 1; m >>= 1) acc += __shfl_xor(acc, m);
        if (lane == 0) outCls[row] = 1.f / (1.f + expf(-(acc + cbp[0])));
    }
}

extern "C" void kernel_launch(void* const* d_in, const int* in_sizes, int n_in,
                              void* d_out, int out_size, void* d_ws, size_t ws_size,
                              hipStream_t stream)
{
    (void)in_sizes; (void)n_in; (void)out_size; (void)ws_size;
    const int N = NN, E = NE, H = HH;
    const size_t NHf = (size_t)N * H;

    const float* fu0 = (const float*)d_in[0];
    const float* fi1 = (const float*)d_in[3];
    const float* fu2 = (const float*)d_in[4];
    const int* eUI0 = (const int*)d_in[6];
    const int* eIU1 = (const int*)d_in[9];
    const float* Wu  = (const float*)d_in[10];
    const float* bu  = (const float*)d_in[11];
    const float* Wi  = (const float*)d_in[12];
    const float* bi  = (const float*)d_in[13];
    const float* gfW = (const float*)d_in[14];
    const float* gfb = (const float*)d_in[15];
    const float* gaw = (const float*)d_in[16];
    const float* gab = (const float*)d_in[17];
    const float* gbias = (const float*)d_in[18];
    const float* prW = (const float*)d_in[19];
    const float* prb = (const float*)d_in[20];
    const float* dW  = (const float*)d_in[21];
    const float* db  = (const float*)d_in[22];
    const float* dlg = (const float*)d_in[23];
    const float* dlb = (const float*)d_in[24];
    const float* rlg = (const float*)d_in[25];
    const float* rlb = (const float*)d_in[26];
    const float* cW  = (const float*)d_in[27];
    const float* cb  = (const float*)d_in[28];

    // fp32 region
    float* B5     = (float*)d_ws;      // residual sc (fp32)
    float* ssb    = B5 + NHf;          // [N]
    float* tsb    = ssb + N;           // [N]
    float* uvall  = tsb + N;           // [2048]
    float* s0t0a  = uvall + 2048;      // [8]
    float* bcomp  = s0t0a + 8;         // [512]
    float* wuv    = bcomp + 512;       // [512]
    float* wiu    = wuv + 512;         // [256] (+pad to 512)
    float* wuu0   = wiu + 512;         // [512]
    float* cpair1 = wuu0 + 512;        // [4]
    float* cpair0 = cpair1 + 4;        // [4]
    float* wvb    = cpair0 + 4;        // [E]
    int* counts0 = (int*)(wvb + E);
    int* counts1 = counts0 + N;
    int* offs0   = counts1 + N;
    int* offs1   = offs0 + N + 1;
    int* cur0    = offs1 + N + 1;
    int* cur1    = cur0 + N;
    int* tvals   = cur1 + N;           // [E]
    int* eidxb   = tvals + E;          // [E]
    size_t boff = (size_t)((char*)(eidxb + E) - (char*)d_ws);
    boff = (boff + 15) & ~(size_t)15;
    short* HU0   = (short*)((char*)d_ws + boff);  // [NHf]
    short* HI    = HU0 + NHf;
    short* SINEW = HI + NHf;
    short* T4    = SINEW + NHf;
    short* SUF   = T4 + NHf;
    short* ZBUF  = SUF + NHf;
    short* WTu   = ZBUF + NHf;
    short* WTi   = WTu + 512 * 512;
    short* WTg0  = WTi + 512 * 256;
    short* WTg1  = WTg0 + 512 * 512;
    short* WTpr  = WTg1 + 512 * 512;
    short* WTd   = WTpr + 512 * 512;
    short* WuB   = WTd + 4 * 512 * 512;
    short* WTcmp = WuB + 512 * 512;
    short* XB  = SINEW;
    short* ZB  = ZBUF;

    // ---- batched pre-passes ----
    hipLaunchKernelGGL(wtr_all, dim3(16, 16, 10), dim3(32, 8), 0, stream,
                       Wu, Wi, gfW, prW, dW, WTu, WTi, WTg0, WTg1, WTpr, WTd, WuB);
    hipMemsetAsync(counts0, 0, 2 * N * sizeof(int), stream);
    hipLaunchKernelGGL(count2_kernel, dim3((2 * E + 255) / 256), dim3(256), 0, stream,
                       eUI0, eIU1, counts0, counts1, E);
    hipLaunchKernelGGL(scan2_kernel, dim3(2), dim3(1024), 0, stream,
                       counts0, counts1, offs0, offs1, cur0, cur1, N);
    hipLaunchKernelGGL(gat_pre2, dim3(130, 2), dim3(256), 0, stream,
                       gfW, gfb, gaw, uvall, s0t0a);
    hipLaunchKernelGGL(wuvbc2_kernel, dim3(130, 4), dim3(256), 0, stream,
                       Wu, bu, Wi, bi, WTg1, gfb + H, uvall, s0t0a,
                       wuv, cpair1, bcomp, wiu, wuu0, cpair0);
    // composed weight WTcmp = WTg1 x WuB (bf16 512x512)
    hipLaunchKernelGGL(mfma_lin, dim3(16), dim3(256), 0, stream,
                       WTg1, WuB, (const float*)nullptr, (float*)nullptr, WTcmp,
                       512, 512, (const float*)nullptr, (const float*)nullptr,
                       (const short*)nullptr, (const float*)nullptr,
                       (const float*)nullptr, ssb, tsb, 0);

    const int rgrid = (N + 3) / 4;
    const int egrid = (E + 255) / 256;
    const int nwg = ((N + 127) / 128) * 4;

    // ---- combined input transforms + GAT1 rowdot (one big launch) ----
    hipLaunchKernelGGL(mfma_multi, dim3(3 * nwg + rgrid), dim3(256), 0, stream,
                       fu0, WTu, bu, HU0,
                       fi1, WTi, bi, HI,
                       fu2, WTcmp, bcomp, T4,
                       N, fi1, wiu, fu2, wuv, cpair1, ssb, tsb, N);

    // ---- GAT1 ----
    hipLaunchKernelGGL(fill_kernel, dim3(egrid), dim3(256), 0, stream,
                       eIU1, eIU1 + E, ssb, tsb, gab + 1, cur1, tvals, wvb,
                       eidxb, E);
    hipLaunchKernelGGL(gat_agg_kernel, dim3(rgrid), dim3(256), 0, stream,
                       offs1, tvals, wvb, eidxb, T4, HI, gbias + H, SINEW, N);

    // ---- GAT0 (T4 = SINEW@WTg0; mixed rowdot: ss=fu0·wuu0+c, ts=SINEW·v0+t0)
    hipLaunchKernelGGL(mfma_lin, dim3(nwg + rgrid), dim3(256), 0, stream,
                       SINEW, WTg0, gfb, (float*)nullptr, T4, N, 512,
                       fu0, wuu0, SINEW, uvall + 512, cpair0, ssb, tsb, N);
    hipLaunchKernelGGL(fill_kernel, dim3(egrid), dim3(256), 0, stream,
                       eUI0, eUI0 + E, ssb, tsb, gab, cur0, tvals, wvb,
                       eidxb, E);
    hipLaunchKernelGGL(gat_agg_kernel, dim3(rgrid), dim3(256), 0, stream,
                       offs0, tvals, wvb, eidxb, T4, HU0, gbias, SUF, N);

    // Res_DNN head
    hipLaunchKernelGGL(mfma_lin, dim3(nwg), dim3(256), 0, stream,
                       SUF, WTpr, prb, B5, XB, N, 512,
                       (const float*)nullptr, (const float*)nullptr,
                       (const short*)nullptr, (const float*)nullptr,
                       (const float*)nullptr, ssb, tsb, 0);
    for (int r = 0; r < 2; ++r) {
        hipLaunchKernelGGL(mfma_lin, dim3(nwg), dim3(256), 0, stream,
                           XB, WTd + (size_t)(r * 2) * 512 * 512, db + (r * 2) * H,
                           (float*)nullptr, ZB, N, 512,
                           (const float*)nullptr, (const float*)nullptr,
                           (const short*)nullptr, (const float*)nullptr,
                           (const float*)nullptr, ssb, tsb, 0);
        hipLaunchKernelGGL(tanh_ln_kernel, dim3(rgrid), dim3(256), 0, stream,
                           ZB, dlg + (r * 2) * H, dlb + (r * 2) * H, XB, N);
        hipLaunchKernelGGL(mfma_lin, dim3(nwg), dim3(256), 0, stream,
                           XB, WTd + (size_t)(r * 2 + 1) * 512 * 512, db + (r * 2 + 1) * H,
                           (float*)nullptr, ZB, N, 512,
                           (const float*)nullptr, (const float*)nullptr,
                           (const short*)nullptr, (const float*)nullptr,
                           (const float*)nullptr, ssb, tsb, 0);
        if (r == 0) {
            hipLaunchKernelGGL(tanh_ln2_kernel, dim3(rgrid), dim3(256), 0, stream,
                               ZB, B5, dlg + H, dlb + H, rlg, rlb,
                               XB, B5, (const float*)nullptr, (const float*)nullptr,
                               (float*)nullptr, N);
        } else {
            hipLaunchKernelGGL(tanh_ln2_kernel, dim3(rgrid), dim3(256), 0, stream,
                               ZB, B5, dlg + 3 * H, dlb + 3 * H, rlg + H, rlb + H,
                               (short*)nullptr, (float*)nullptr, cW, cb,
                               (float*)d_out, N);
        }
    }
}

// Round 20
// 493.115 us; speedup vs baseline: 1.0152x; 1.0152x over previous
//
#include <hip/hip_runtime.h>
#include <math.h>

#define NN 20000
#define NE 200000
#define HH 512

typedef __attribute__((ext_vector_type(8))) short short8v;
typedef __attribute__((ext_vector_type(4))) float f32x4;

__device__ inline short f2bf(float f) {
    union { float f; unsigned u; } v; v.f = f;
    unsigned r = (v.u + 0x7fffu + ((v.u >> 16) & 1u)) >> 16;
    return (short)r;
}
__device__ inline float bf2f(short s) {
    union { unsigned u; float f; } v;
    v.u = ((unsigned)(unsigned short)s) << 16;
    return v.f;
}

__device__ inline void gload_lds16(const void* g, void* l) {
    __builtin_amdgcn_global_load_lds(
        (const __attribute__((address_space(1))) void*)g,
        (__attribute__((address_space(3))) void*)l, 16, 0, 0);
}

// ---------------- batched weight transpose+bf16 (+ z=9: plain Wu convert) ---
__global__ __launch_bounds__(256)
void wtr_all(const float* __restrict__ Wu, const float* __restrict__ Wi,
             const float* __restrict__ gfW, const float* __restrict__ prW,
             const float* __restrict__ dW,
             short* __restrict__ WTu, short* __restrict__ WTi,
             short* __restrict__ WTg0, short* __restrict__ WTg1,
             short* __restrict__ WTpr, short* __restrict__ WTd,
             short* __restrict__ WuB)
{
    __shared__ float t[32][33];
    int z = blockIdx.z;
    int by = blockIdx.y * 32;
    int bx = blockIdx.x * 32;
    int tx = threadIdx.x, ty = threadIdx.y;
    if (z == 9) {
        for (int i = ty; i < 32; i += 8)
            WuB[(size_t)(by + i) * 512 + bx + tx] =
                f2bf(Wu[(size_t)(by + i) * 512 + bx + tx]);
        return;
    }
    const float* src; short* dst; int K;
    if (z == 0)      { src = Wu;  dst = WTu;  K = 512; }
    else if (z == 1) { src = Wi;  dst = WTi;  K = 256; }
    else if (z == 2) { src = gfW; dst = WTg0; K = 512; }
    else if (z == 3) { src = gfW + (size_t)512 * 512; dst = WTg1; K = 512; }
    else if (z == 4) { src = prW; dst = WTpr; K = 512; }
    else { src = dW + (size_t)(z - 5) * 512 * 512;
           dst = WTd + (size_t)(z - 5) * 512 * 512; K = 512; }
    if (by >= K) return;
    for (int i = ty; i < 32; i += 8)
        t[i][tx] = src[(size_t)(by + i) * 512 + bx + tx];
    __syncthreads();
    for (int i = ty; i < 32; i += 8)
        dst[(size_t)(bx + i) * K + by + tx] = f2bf(t[tx][i]);
}

// ---------------- MFMA GEMM (128x128, BK=64, 2-stage counted vmcnt) ---------
// bf16 A; nullable bias; optional MIXED rowdot tail:
// ss = fp32 rdF(512)·rdfv + rdc[0] ; ts = bf16 rdB(512)·rdbv + rdc[1]
__global__ __launch_bounds__(256)
void mfma_lin(const short* __restrict__ X, const short* __restrict__ WT,
              const float* __restrict__ bias, float* __restrict__ outF,
              short* __restrict__ outB, int M, int K,
              const float* __restrict__ rdF, const float* __restrict__ rdfv,
              const short* __restrict__ rdB, const float* __restrict__ rdbv,
              const float* __restrict__ rdc, float* __restrict__ rdss,
              float* __restrict__ rdts, int rdN)
{
    __shared__ short8v pool[4096];   // 64 KB

    const int tid = threadIdx.x;
    const int lane = tid & 63;
    const int w = tid >> 6;

    const int nby = (M + 127) >> 7;
    const int nwg = nby << 2;
    int id = blockIdx.x;

    if (id >= nwg) {                 // ---------- mixed rowdot role ----------
        int row = (id - nwg) * 4 + w;
        if (!rdF || row >= rdN) return;
        const float4* fp = (const float4*)(rdF + (size_t)row * HH) + lane * 2;
        float4 f0 = fp[0], f1 = fp[1];
        const float4* up = (const float4*)rdfv + lane * 2;
        float4 u0 = up[0], u1 = up[1];
        float a = f0.x*u0.x + f0.y*u0.y + f0.z*u0.z + f0.w*u0.w
                + f1.x*u1.x + f1.y*u1.y + f1.z*u1.z + f1.w*u1.w;
        short8v t = ((const short8v*)(rdB + (size_t)row * HH))[lane];
        const float4* vp = (const float4*)rdbv + lane * 2;
        float4 v0 = vp[0], v1 = vp[1];
        float b = bf2f(t[0])*v0.x + bf2f(t[1])*v0.y + bf2f(t[2])*v0.z + bf2f(t[3])*v0.w
                + bf2f(t[4])*v1.x + bf2f(t[5])*v1.y + bf2f(t[6])*v1.z + bf2f(t[7])*v1.w;
#pragma unroll
        for (int m = 32; m >= 1; m >>= 1) {
            a += __shfl_xor(a, m);
            b += __shfl_xor(b, m);
        }
        if (lane == 0) { rdss[row] = a + rdc[0]; rdts[row] = b + rdc[1]; }
        return;
    }

    // ---------- GEMM role ----------
    const int q = nwg >> 3, r = nwg & 7;
    int xcd = id & 7, wi = id >> 3;
    int wgid = (xcd < r ? xcd * (q + 1) : r * (q + 1) + (xcd - r) * q) + wi;
    const int col0 = (wgid & 3) * 128;
    const int row0 = (wgid >> 2) * 128;

    const int wr = (w >> 1) * 64;
    const int wc = (w & 1) * 64;

    const short* gsrc[8];
#pragma unroll
    for (int g = 0; g < 8; ++g) {
        int p = w * 512 + g * 64 + lane;
        if (p < 1024) {
            int row = p >> 3;
            int c = (p & 7) ^ (row & 7);
            int ga = row0 + row; if (ga >= M) ga = M - 1;
            gsrc[g] = X + (size_t)ga * K + c * 8;
        } else {
            int qq = p - 1024;
            int col = qq >> 3;
            int c = (qq & 7) ^ (col & 7);
            gsrc[g] = WT + (size_t)(col0 + col) * K + c * 8;
        }
    }

    int ar[2][4], br[2][4];
#pragma unroll
    for (int kk = 0; kk < 2; ++kk) {
#pragma unroll
        for (int i = 0; i < 4; ++i) {
            int rr = wr + i * 16 + (lane & 15);
            ar[kk][i] = rr * 8 + ((kk * 4 + (lane >> 4)) ^ (rr & 7));
            int nn = wc + i * 16 + (lane & 15);
            br[kk][i] = 1024 + nn * 8 + ((kk * 4 + (lane >> 4)) ^ (nn & 7));
        }
    }

    f32x4 acc[4][4];
#pragma unroll
    for (int i = 0; i < 4; ++i)
#pragma unroll
        for (int j = 0; j < 4; ++j)
            acc[i][j] = (f32x4){0.f, 0.f, 0.f, 0.f};

    auto stage = [&](int buf, int kk) {
        short8v* base = pool + buf * 2048 + w * 512;
#pragma unroll
        for (int g = 0; g < 8; ++g)
            gload_lds16(gsrc[g] + kk, base + g * 64);
    };

    const int nt = K >> 6;
    stage(0, 0);
    if (nt > 1) stage(1, 64);
    int cur = 0;
    for (int t = 0; t < nt; ++t) {
        if (t + 1 < nt) asm volatile("s_waitcnt vmcnt(8)" ::: "memory");
        else            asm volatile("s_waitcnt vmcnt(0)" ::: "memory");
        __builtin_amdgcn_s_barrier();
        const short8v* S = pool + cur * 2048;
#pragma unroll
        for (int kk = 0; kk < 2; ++kk) {
            short8v af[4], bf[4];
#pragma unroll
            for (int i = 0; i < 4; ++i) af[i] = S[ar[kk][i]];
#pragma unroll
            for (int j = 0; j < 4; ++j) bf[j] = S[br[kk][j]];
#pragma unroll
            for (int i = 0; i < 4; ++i)
#pragma unroll
                for (int j = 0; j < 4; ++j)
                    acc[i][j] = __builtin_amdgcn_mfma_f32_16x16x32_bf16(af[i], bf[j], acc[i][j], 0, 0, 0);
        }
        __builtin_amdgcn_s_barrier();
        if (t + 2 < nt) stage(cur, (t + 2) * 64);
        cur ^= 1;
    }

    float bj[4];
#pragma unroll
    for (int j = 0; j < 4; ++j)
        bj[j] = bias ? bias[col0 + wc + j * 16 + (lane & 15)] : 0.f;

    if (outF) {
#pragma unroll
        for (int i = 0; i < 4; ++i) {
#pragma unroll
            for (int rr = 0; rr < 4; ++rr) {
                int row = row0 + wr + i * 16 + (lane >> 4) * 4 + rr;
                if (row < M) {
                    float* op = outF + (size_t)row * HH + col0 + wc + (lane & 15);
#pragma unroll
                    for (int j = 0; j < 4; ++j) op[j * 16] = acc[i][j][rr] + bj[j];
                }
            }
        }
    }
    if (outB) {
        short* lt = (short*)pool;    // [128][136] bf16
#pragma unroll
        for (int i = 0; i < 4; ++i)
#pragma unroll
            for (int rr = 0; rr < 4; ++rr) {
                int lrow = wr + i * 16 + (lane >> 4) * 4 + rr;
#pragma unroll
                for (int j = 0; j < 4; ++j)
                    lt[lrow * 136 + wc + j * 16 + (lane & 15)] = f2bf(acc[i][j][rr] + bj[j]);
            }
        __syncthreads();
#pragma unroll
        for (int k = 0; k < 8; ++k) {
            int row = (tid >> 4) + 16 * k;
            int seg = tid & 15;
            int grow = row0 + row;
            if (grow < M) {
                short8v vv = *(short8v*)(lt + row * 136 + seg * 8);
                *(short8v*)(outB + (size_t)grow * HH + col0 + seg * 8) = vv;
            }
        }
    }
}

// ---------------- mfma_multi: 3 independent fp32-A GEMMs + GAT1 rowdot ------
__global__ __launch_bounds__(256)
void mfma_multi(const float* __restrict__ A0, const short* __restrict__ W0,
                const float* __restrict__ b0, short* __restrict__ O0,
                const float* __restrict__ A1, const short* __restrict__ W1,
                const float* __restrict__ b1, short* __restrict__ O1,
                const float* __restrict__ A2, const short* __restrict__ W2,
                const float* __restrict__ b2, short* __restrict__ O2,
                int M,
                const float* __restrict__ rdF1, const float* __restrict__ rdv1,
                const float* __restrict__ rdF2, const float* __restrict__ rdv2,
                const float* __restrict__ rdc, float* __restrict__ rdss,
                float* __restrict__ rdts, int rdN)
{
    __shared__ short8v pool[2304];   // 36 KB

    const int tid = threadIdx.x;
    const int lane = tid & 63;
    const int w = tid >> 6;

    const int nby = (M + 127) >> 7;
    const int nwg = nby << 2;
    int id = blockIdx.x;

    if (id >= 3 * nwg) {             // ---------- GAT1 rowdot (raw inputs) ----
        int row = (id - 3 * nwg) * 4 + w;
        if (row >= rdN) return;
        const float4* fp = (const float4*)(rdF1 + (size_t)row * 256) + lane;
        float4 f = fp[0];
        const float4* u1p = (const float4*)rdv1 + lane;
        float4 u1 = u1p[0];
        float a = f.x*u1.x + f.y*u1.y + f.z*u1.z + f.w*u1.w;
        const float4* tp = (const float4*)(rdF2 + (size_t)row * HH) + lane * 2;
        float4 t0v = tp[0], t1v = tp[1];
        const float4* vp = (const float4*)rdv2 + lane * 2;
        float4 v0 = vp[0], v1 = vp[1];
        float b = t0v.x*v0.x + t0v.y*v0.y + t0v.z*v0.z + t0v.w*v0.w
                + t1v.x*v1.x + t1v.y*v1.y + t1v.z*v1.z + t1v.w*v1.w;
#pragma unroll
        for (int m = 32; m >= 1; m >>= 1) {
            a += __shfl_xor(a, m);
            b += __shfl_xor(b, m);
        }
        if (lane == 0) { rdss[row] = a + rdc[0]; rdts[row] = b + rdc[1]; }
        return;
    }

    // ---------- GEMM role, segment select ----------
    int seg = id / nwg;
    int sid = id - seg * nwg;
    const float* XA = (seg == 0) ? A0 : ((seg == 1) ? A1 : A2);
    const short* WT = (seg == 0) ? W0 : ((seg == 1) ? W1 : W2);
    const float* bias = (seg == 0) ? b0 : ((seg == 1) ? b1 : b2);
    short* outB = (seg == 0) ? O0 : ((seg == 1) ? O1 : O2);
    const int K = (seg == 1) ? 256 : 512;

    const int q = nwg >> 3, r = nwg & 7;
    int xcd = sid & 7, wi = sid >> 3;
    int wgid = (xcd < r ? xcd * (q + 1) : r * (q + 1) + (xcd - r) * q) + wi;
    const int col0 = (wgid & 3) * 128;
    const int row0 = (wgid >> 2) * 128;

    const int wr = (w >> 1) * 64;
    const int wc = (w & 1) * 64;

    const int srow = tid >> 1;
    const int sc0 = (tid & 1) * 2;
    int garow = row0 + srow; if (garow >= M) garow = M - 1;
    const float* abase = XA + (size_t)garow * K + sc0 * 8;
    const int aswz = (srow >> 1) & 3;
    const int wi0 = srow * 4 + (sc0 ^ aswz);
    const int wi1 = srow * 4 + ((sc0 + 1) ^ aswz);

    const short* bsrc0; const short* bsrc1;
    int bbase0, bbase1;
    {
        int p0 = w * 128 + lane;
        int col = p0 >> 2;
        int c = (p0 & 3) ^ ((col >> 1) & 3);
        bsrc0 = WT + (size_t)(col0 + col) * K + c * 8;
        bbase0 = w * 128;
        int p1 = w * 128 + 64 + lane;
        col = p1 >> 2;
        c = (p1 & 3) ^ ((col >> 1) & 3);
        bsrc1 = WT + (size_t)(col0 + col) * K + c * 8;
        bbase1 = w * 128 + 64;
    }

    int ar[4], br[4];
#pragma unroll
    for (int i = 0; i < 4; ++i) {
        int rr = wr + i * 16 + (lane & 15);
        ar[i] = rr * 4 + ((lane >> 4) ^ ((rr >> 1) & 3));
        int nn = wc + i * 16 + (lane & 15);
        br[i] = 512 + nn * 4 + ((lane >> 4) ^ ((nn >> 1) & 3));
    }

    f32x4 acc[4][4];
#pragma unroll
    for (int i = 0; i < 4; ++i)
#pragma unroll
        for (int j = 0; j < 4; ++j)
            acc[i][j] = (f32x4){0.f, 0.f, 0.f, 0.f};

    const int nt = K >> 5;            // 16 or 8 (even)
    float4 rA0[4], rA1[4];

#define ISSUE_A(RA, T) {                                                   \
        const float4* p_ = (const float4*)(abase + (T) * 32);              \
        RA[0] = p_[0]; RA[1] = p_[1]; RA[2] = p_[2]; RA[3] = p_[3]; }
#define ISSUE_B(BUF, T) {                                                  \
        short8v* bb_ = pool + (BUF) * 1024 + 512;                          \
        gload_lds16(bsrc0 + (T) * 32, bb_ + bbase0);                       \
        gload_lds16(bsrc1 + (T) * 32, bb_ + bbase1); }
#define LINF_BODY(BUF, RA, T) {                                            \
        short8v s0_, s1_;                                                  \
        s0_[0]=f2bf(RA[0].x); s0_[1]=f2bf(RA[0].y); s0_[2]=f2bf(RA[0].z); s0_[3]=f2bf(RA[0].w); \
        s0_[4]=f2bf(RA[1].x); s0_[5]=f2bf(RA[1].y); s0_[6]=f2bf(RA[1].z); s0_[7]=f2bf(RA[1].w); \
        s1_[0]=f2bf(RA[2].x); s1_[1]=f2bf(RA[2].y); s1_[2]=f2bf(RA[2].z); s1_[3]=f2bf(RA[2].w); \
        s1_[4]=f2bf(RA[3].x); s1_[5]=f2bf(RA[3].y); s1_[6]=f2bf(RA[3].z); s1_[7]=f2bf(RA[3].w); \
        short8v* A_ = pool + (BUF) * 1024;                                 \
        A_[wi0] = s0_; A_[wi1] = s1_;                                      \
        if ((T) + 1 < nt) asm volatile("s_waitcnt vmcnt(6) lgkmcnt(0)" ::: "memory"); \
        else              asm volatile("s_waitcnt vmcnt(0) lgkmcnt(0)" ::: "memory"); \
        __builtin_amdgcn_s_barrier();                                      \
        const short8v* S_ = pool + (BUF) * 1024;                           \
        short8v af_[4], bf_[4];                                            \
        _Pragma("unroll")                                                  \
        for (int i_ = 0; i_ < 4; ++i_) af_[i_] = S_[ar[i_]];               \
        _Pragma("unroll")                                                  \
        for (int j_ = 0; j_ < 4; ++j_) bf_[j_] = S_[br[j_]];               \
        _Pragma("unroll")                                                  \
        for (int i_ = 0; i_ < 4; ++i_)                                     \
            _Pragma("unroll")                                              \
            for (int j_ = 0; j_ < 4; ++j_)                                 \
                acc[i_][j_] = __builtin_amdgcn_mfma_f32_16x16x32_bf16(af_[i_], bf_[j_], acc[i_][j_], 0, 0, 0); \
        __builtin_amdgcn_s_barrier();                                      \
        if ((T) + 2 < nt) { ISSUE_A(RA, (T) + 2); ISSUE_B(BUF, (T) + 2); } }

    ISSUE_A(rA0, 0);
    ISSUE_B(0, 0);
    ISSUE_A(rA1, 1);
    ISSUE_B(1, 1);
    for (int t = 0; t < nt; t += 2) {
        LINF_BODY(0, rA0, t);
        LINF_BODY(1, rA1, t + 1);
    }
#undef ISSUE_A
#undef ISSUE_B
#undef LINF_BODY

    float bj[4];
#pragma unroll
    for (int j = 0; j < 4; ++j)
        bj[j] = bias[col0 + wc + j * 16 + (lane & 15)];

    short* lt = (short*)pool;
#pragma unroll
    for (int i = 0; i < 4; ++i)
#pragma unroll
        for (int rr = 0; rr < 4; ++rr) {
            int lrow = wr + i * 16 + (lane >> 4) * 4 + rr;
#pragma unroll
            for (int j = 0; j < 4; ++j)
                lt[lrow * 136 + wc + j * 16 + (lane & 15)] = f2bf(acc[i][j][rr] + bj[j]);
        }
    __syncthreads();
#pragma unroll
    for (int k = 0; k < 8; ++k) {
        int row = (tid >> 4) + 16 * k;
        int seg2 = tid & 15;
        int grow = row0 + row;
        if (grow < M) {
            short8v vv = *(short8v*)(lt + row * 136 + seg2 * 8);
            *(short8v*)(outB + (size_t)grow * HH + col0 + seg2 * 8) = vv;
        }
    }
}

// ---------------- gat_pre for BOTH relations (one launch) -------------------
__global__ __launch_bounds__(256)
void gat_pre2(const float* __restrict__ gfW, const float* __restrict__ gfb,
              const float* __restrict__ gaw, float* __restrict__ uvall,
              float* __restrict__ s0t0all)
{
    int rrel = blockIdx.y;
    const float* fW = gfW + (size_t)rrel * HH * HH;
    const float* fb = gfb + rrel * HH;
    const float* aw = gaw + (size_t)rrel * 2 * HH;
    float* uv = uvall + rrel * 1024;
    float* s0t0 = s0t0all + rrel * 4;
    int row = blockIdx.x * 4 + (threadIdx.x >> 6);
    int lane = threadIdx.x & 63;
    const float4* ah = (const float4*)aw;
    const float4* at = (const float4*)(aw + HH);
    const float4* fp;
    if (row < 512)       fp = (const float4*)(fW + (size_t)row * HH);
    else if (row == 512) fp = (const float4*)fb;
    else return;
    float du = 0.f, dv = 0.f;
#pragma unroll
    for (int l = 0; l < 2; ++l) {
        int idx = lane * 2 + l;
        float4 f = fp[idx], a = ah[idx], b = at[idx];
        du += f.x*a.x + f.y*a.y + f.z*a.z + f.w*a.w;
        dv += f.x*b.x + f.y*b.y + f.z*b.z + f.w*b.w;
    }
#pragma unroll
    for (int m = 32; m >= 1; m >>= 1) {
        du += __shfl_xor(du, m);
        dv += __shfl_xor(dv, m);
    }
    if (lane == 0) {
        if (row < 512) { uv[row] = du; uv[512 + row] = dv; }
        else           { s0t0[0] = du; s0t0[1] = dv; }
    }
}

// ---------------- wuvbc2: composition vectors for both GATs ----------------
__global__ __launch_bounds__(256)
void wuvbc2_kernel(const float* __restrict__ Wu, const float* __restrict__ bu,
                   const float* __restrict__ Wi, const float* __restrict__ bi,
                   const short* __restrict__ WTg1, const float* __restrict__ fb1,
                   const float* __restrict__ uvall, const float* __restrict__ s0t0a,
                   float* __restrict__ wuv, float* __restrict__ cpair1,
                   float* __restrict__ bcomp, float* __restrict__ wiu,
                   float* __restrict__ wuu0, float* __restrict__ cpair0)
{
    int row = blockIdx.x * 4 + (threadIdx.x >> 6);
    int lane = threadIdx.x & 63;
    int y = blockIdx.y;
    if (y == 0 || y == 3) {
        const float* vec = (y == 0) ? (uvall + 1024 + 512) : (uvall + 0);
        const float4* vp = (const float4*)vec + lane * 2;
        float4 v0 = vp[0], v1v = vp[1];
        const float4* fp;
        if (row < 512)       fp = (const float4*)(Wu + (size_t)row * HH);
        else if (row == 512) fp = (const float4*)bu;
        else return;
        const float4* p = fp + lane * 2;
        float4 a = p[0], b = p[1];
        float d = a.x*v0.x + a.y*v0.y + a.z*v0.z + a.w*v0.w
                + b.x*v1v.x + b.y*v1v.y + b.z*v1v.z + b.w*v1v.w;
#pragma unroll
        for (int m = 32; m >= 1; m >>= 1) d += __shfl_xor(d, m);
        if (lane == 0) {
            if (y == 0) {
                if (row < 512) wuv[row] = d;
                else           cpair1[1] = d + s0t0a[5];
            } else {
                if (row < 512) wuu0[row] = d;
                else { cpair0[0] = d + s0t0a[0]; cpair0[1] = s0t0a[1]; }
            }
        }
    } else if (y == 1) {
        if (row >= 512) return;
        short8v wv8 = ((const short8v*)(WTg1 + (size_t)row * HH))[lane];
        const float4* bp = (const float4*)bu + lane * 2;
        float4 b0 = bp[0], b1 = bp[1];
        float d = bf2f(wv8[0])*b0.x + bf2f(wv8[1])*b0.y + bf2f(wv8[2])*b0.z + bf2f(wv8[3])*b0.w
                + bf2f(wv8[4])*b1.x + bf2f(wv8[5])*b1.y + bf2f(wv8[6])*b1.z + bf2f(wv8[7])*b1.w;
#pragma unroll
        for (int m = 32; m >= 1; m >>= 1) d += __shfl_xor(d, m);
        if (lane == 0) bcomp[row] = d + fb1[row];
    } else {   // y == 2
        const float* u1 = uvall + 1024;
        const float4* vp = (const float4*)u1 + lane * 2;
        float4 v0 = vp[0], v1v = vp[1];
        const float4* fp;
        if (row < 256)       fp = (const float4*)(Wi + (size_t)row * HH);
        else if (row == 256) fp = (const float4*)bi;
        else return;
        const float4* p = fp + lane * 2;
        float4 a = p[0], b = p[1];
        float d = a.x*v0.x + a.y*v0.y + a.z*v0.z + a.w*v0.w
                + b.x*v1v.x + b.y*v1v.y + b.z*v1v.z + b.w*v1v.w;
#pragma unroll
        for (int m = 32; m >= 1; m >>= 1) d += __shfl_xor(d, m);
        if (lane == 0) {
            if (row < 256) wiu[row] = d;
            else           cpair1[0] = d + s0t0a[4];
        }
    }
}

// ---------------- CSR build ----------------
__global__ __launch_bounds__(256)
void count2_kernel(const int* __restrict__ s0, const int* __restrict__ s1,
                   int* __restrict__ c0, int* __restrict__ c1, int E)
{
    int i = blockIdx.x * blockDim.x + threadIdx.x;
    if (i < E) atomicAdd(&c0[s0[i]], 1);
    else if (i < 2 * E) atomicAdd(&c1[s1[i - E]], 1);
}

__global__ __launch_bounds__(1024)
void scan2_kernel(const int* __restrict__ c0, const int* __restrict__ c1,
                  int* __restrict__ o0, int* __restrict__ o1,
                  int* __restrict__ u0, int* __restrict__ u1, int n)
{
    const int* counts = blockIdx.x ? c1 : c0;
    int* offs = blockIdx.x ? o1 : o0;
    int* curs = blockIdx.x ? u1 : u0;
    __shared__ int part[1024];
    const int tid = threadIdx.x;
    const int CH = (n + 1023) / 1024;
    const int base = tid * CH;
    int s = 0;
    for (int i = 0; i < CH; ++i) {
        int idx = base + i;
        if (idx < n) s += counts[idx];
    }
    part[tid] = s;
    __syncthreads();
    for (int d = 1; d < 1024; d <<= 1) {
        int v = 0;
        if (tid >= d) v = part[tid - d];
        __syncthreads();
        if (tid >= d) part[tid] += v;
        __syncthreads();
    }
    int run = (tid == 0) ? 0 : part[tid - 1];
    for (int i = 0; i < CH; ++i) {
        int idx = base + i;
        if (idx < n) { offs[idx] = run; curs[idx] = run; run += counts[idx]; }
    }
    if (tid == 1023) offs[n] = run;
}

__global__ __launch_bounds__(256)
void fill_kernel(const int* __restrict__ src, const int* __restrict__ tgt,
                 const float* __restrict__ ss, const float* __restrict__ ts,
                 const float* __restrict__ ab_ptr, int* __restrict__ cursor,
                 int* __restrict__ tvals, float* __restrict__ wv,
                 int* __restrict__ eidx, int E)
{
    int i = blockIdx.x * blockDim.x + threadIdx.x;
    if (i >= E) return;
    int s = src[i], t = tgt[i];
    int pos = atomicAdd(&cursor[s], 1);
    tvals[pos] = t;
    wv[pos] = expf(tanhf(ss[s] + ts[t] + ab_ptr[0]));
    eidx[pos] = i;
}

// ---------------- fused GAT: in-wave canonical sort + aggregate + combine ---
__global__ __launch_bounds__(256)
void gat_agg_kernel(const int* __restrict__ offs, const int* __restrict__ tvals,
                    const float* __restrict__ wv, const int* __restrict__ eidx,
                    const short* __restrict__ T, const short* __restrict__ head,
                    const float* __restrict__ gbias, short* __restrict__ out, int N)
{
    __shared__ int   slt[4][512];
    __shared__ float slw[4][512];
    int w = threadIdx.x >> 6;
    int lane = threadIdx.x & 63;
    int s = blockIdx.x * 4 + w;
    if (s >= N) return;
    const int beg = offs[s], end = offs[s + 1];
    int L = end - beg;
    if (L > 512) L = 512;

    if (L <= 64) {
        int e = 0x7fffffff, t = 0; float fw = 0.f;
        if (lane < L) { e = eidx[beg + lane]; t = tvals[beg + lane]; fw = wv[beg + lane]; }
        int r = 0;
        for (int k = 0; k < L; ++k)
            r += (__shfl(e, k) < e) ? 1 : 0;
        if (lane < L) { slt[w][r] = t; slw[w][r] = fw; }
    } else {
        for (int j = lane; j < L; j += 64) {
            int e = eidx[beg + j];
            int r = 0;
            for (int k = 0; k < L; ++k) r += (eidx[beg + k] < e) ? 1 : 0;
            slt[w][r] = tvals[beg + j]; slw[w][r] = wv[beg + j];
        }
    }
    asm volatile("s_waitcnt lgkmcnt(0)" ::: "memory");

    float a[8];
#pragma unroll
    for (int q = 0; q < 8; ++q) a[q] = 0.f;
    float den = 0.f;

    int j = 0;
    for (; j + 8 <= L; j += 8) {
        short8v v[8];
        float wgt[8];
#pragma unroll
        for (int u = 0; u < 8; ++u) {
            wgt[u] = slw[w][j + u];
            v[u] = ((const short8v*)(T + (size_t)slt[w][j + u] * HH))[lane];
        }
#pragma unroll
        for (int u = 0; u < 8; ++u) {
            den += wgt[u];
#pragma unroll
            for (int q = 0; q < 8; ++q) a[q] = fmaf(wgt[u], bf2f(v[u][q]), a[q]);
        }
    }
    for (; j + 4 <= L; j += 4) {
        short8v v[4];
        float wgt[4];
#pragma unroll
        for (int u = 0; u < 4; ++u) {
            wgt[u] = slw[w][j + u];
            v[u] = ((const short8v*)(T + (size_t)slt[w][j + u] * HH))[lane];
        }
#pragma unroll
        for (int u = 0; u < 4; ++u) {
            den += wgt[u];
#pragma unroll
            for (int q = 0; q < 8; ++q) a[q] = fmaf(wgt[u], bf2f(v[u][q]), a[q]);
        }
    }
    for (; j < L; ++j) {
        float fw = slw[w][j];
        short8v tv = ((const short8v*)(T + (size_t)slt[w][j] * HH))[lane];
        den += fw;
#pragma unroll
        for (int q = 0; q < 8; ++q) a[q] = fmaf(fw, bf2f(tv[q]), a[q]);
    }
    float inv = (den > 0.f) ? 1.f / den : 0.f;

    short8v h = ((const short8v*)(head + (size_t)s * HH))[lane];
    const float4* bp = (const float4*)gbias + lane * 2;
    float4 b0 = bp[0], b1 = bp[1];
    float bb[8] = {b0.x, b0.y, b0.z, b0.w, b1.x, b1.y, b1.z, b1.w};
    short8v o;
#pragma unroll
    for (int q = 0; q < 8; ++q)
        o[q] = f2bf((bf2f(h[q]) + a[q] * inv + bb[q]) * 0.5f);
    ((short8v*)(out + (size_t)s * HH))[lane] = o;
}

// ---------------- single tanh+LN (d=0 layers) -------------------------------
__global__ __launch_bounds__(256)
void tanh_ln_kernel(const short* __restrict__ Z,
                    const float* __restrict__ g, const float* __restrict__ bta,
                    short* __restrict__ outB, int N)
{
    int row = blockIdx.x * 4 + (threadIdx.x >> 6);
    int lane = threadIdx.x & 63;
    if (row >= N) return;
    short8v zv = ((const short8v*)(Z + (size_t)row * HH))[lane];
    float v[8];
    float sum = 0.f, sum2 = 0.f;
#pragma unroll
    for (int q = 0; q < 8; ++q) {
        float t = tanhf(bf2f(zv[q]));
        v[q] = t; sum += t; sum2 = fmaf(t, t, sum2);
    }
#pragma unroll
    for (int m = 32; m >= 1; m >>= 1) {
        sum += __shfl_xor(sum, m); sum2 += __shfl_xor(sum2, m);
    }
    float mu = sum * (1.f/HH);
    float rs = rsqrtf(sum2 * (1.f/HH) - mu*mu + 1e-5f);
    const float4* gp = (const float4*)g + lane * 2;
    const float4* bp = (const float4*)bta + lane * 2;
    float4 g0 = gp[0], g1 = gp[1], c0 = bp[0], c1 = bp[1];
    float gg[8] = {g0.x, g0.y, g0.z, g0.w, g1.x, g1.y, g1.z, g1.w};
    float cc[8] = {c0.x, c0.y, c0.z, c0.w, c1.x, c1.y, c1.z, c1.w};
    short8v ob;
#pragma unroll
    for (int q = 0; q < 8; ++q) ob[q] = f2bf((v[q]-mu)*rs*gg[q] + cc[q]);
    ((short8v*)(outB + (size_t)row * HH))[lane] = ob;
}

// ---------------- fused double LN (d=1 + residual) --------------------------
__global__ __launch_bounds__(256)
void tanh_ln2_kernel(const short* __restrict__ Z, const float* __restrict__ sc,
                     const float* __restrict__ g1, const float* __restrict__ b1,
                     const float* __restrict__ g2, const float* __restrict__ b2,
                     short* __restrict__ outB, float* __restrict__ outF,
                     const float* __restrict__ cWp, const float* __restrict__ cbp,
                     float* __restrict__ outCls, int N)
{
    int row = blockIdx.x * 4 + (threadIdx.x >> 6);
    int lane = threadIdx.x & 63;
    if (row >= N) return;
    short8v zv = ((const short8v*)(Z + (size_t)row * HH))[lane];
    float v[8];
    float sum = 0.f, sum2 = 0.f;
#pragma unroll
    for (int q = 0; q < 8; ++q) {
        float t = tanhf(bf2f(zv[q]));
        v[q] = t; sum += t; sum2 = fmaf(t, t, sum2);
    }
#pragma unroll
    for (int m = 32; m >= 1; m >>= 1) {
        sum += __shfl_xor(sum, m); sum2 += __shfl_xor(sum2, m);
    }
    float mu = sum * (1.f/HH);
    float rs = rsqrtf(sum2 * (1.f/HH) - mu*mu + 1e-5f);
    {
        const float4* gp = (const float4*)g1 + lane * 2;
        const float4* bp = (const float4*)b1 + lane * 2;
        float4 g0 = gp[0], g1v = gp[1], c0 = bp[0], c1 = bp[1];
        float gg[8] = {g0.x, g0.y, g0.z, g0.w, g1v.x, g1v.y, g1v.z, g1v.w};
        float cc[8] = {c0.x, c0.y, c0.z, c0.w, c1.x, c1.y, c1.z, c1.w};
        const float4* sp = (const float4*)(sc + (size_t)row * HH) + lane * 2;
        float4 s0 = sp[0], s1 = sp[1];
        float ssv[8] = {s0.x, s0.y, s0.z, s0.w, s1.x, s1.y, s1.z, s1.w};
        sum = 0.f; sum2 = 0.f;
#pragma unroll
        for (int q = 0; q < 8; ++q) {
            float x2 = (v[q]-mu)*rs*gg[q] + cc[q];
            float t = tanhf(ssv[q] + x2);
            v[q] = t; sum += t; sum2 = fmaf(t, t, sum2);
        }
    }
#pragma unroll
    for (int m = 32; m >= 1; m >>= 1) {
        sum += __shfl_xor(sum, m); sum2 += __shfl_xor(sum2, m);
    }
    mu = sum * (1.f/HH);
    rs = rsqrtf(sum2 * (1.f/HH) - mu*mu + 1e-5f);
    const float4* gp = (const float4*)g2 + lane * 2;
    const float4* bp = (const float4*)b2 + lane * 2;
    float4 g0 = gp[0], g1v = gp[1], c0 = bp[0], c1 = bp[1];
    float gg[8] = {g0.x, g0.y, g0.z, g0.w, g1v.x, g1v.y, g1v.z, g1v.w};
    float cc[8] = {c0.x, c0.y, c0.z, c0.w, c1.x, c1.y, c1.z, c1.w};
    float o[8];
#pragma unroll
    for (int q = 0; q < 8; ++q) o[q] = (v[q]-mu)*rs*gg[q] + cc[q];
    if (outB) {
        short8v ob;
#pragma unroll
        for (int q = 0; q < 8; ++q) ob[q] = f2bf(o[q]);
        ((short8v*)(outB + (size_t)row * HH))[lane] = ob;
    }
    if (outF) {
        float4* op = (float4*)(outF + (size_t)row * HH) + lane * 2;
        op[0] = make_float4(o[0], o[1], o[2], o[3]);
        op[1] = make_float4(o[4], o[5], o[6], o[7]);
    }
    if (cWp) {
        const float4* wp = (const float4*)cWp + lane * 2;
        float4 w0 = wp[0], w1 = wp[1];
        float acc = o[0]*w0.x + o[1]*w0.y + o[2]*w0.z + o[3]*w0.w
                  + o[4]*w1.x + o[5]*w1.y + o[6]*w1.z + o[7]*w1.w;
#pragma unroll
        for (int m = 32; m >= 1; m >>= 1) acc += __shfl_xor(acc, m);
        if (lane == 0) outCls[row] = 1.f / (1.f + expf(-(acc + cbp[0])));
    }
}

extern "C" void kernel_launch(void* const* d_in, const int* in_sizes, int n_in,
                              void* d_out, int out_size, void* d_ws, size_t ws_size,
                              hipStream_t stream)
{
    (void)in_sizes; (void)n_in; (void)out_size; (void)ws_size;
    const int N = NN, E = NE, H = HH;
    const size_t NHf = (size_t)N * H;

    const float* fu0 = (const float*)d_in[0];
    const float* fi1 = (const float*)d_in[3];
    const float* fu2 = (const float*)d_in[4];
    const int* eUI0 = (const int*)d_in[6];
    const int* eIU1 = (const int*)d_in[9];
    const float* Wu  = (const float*)d_in[10];
    const float* bu  = (const float*)d_in[11];
    const float* Wi  = (const float*)d_in[12];
    const float* bi  = (const float*)d_in[13];
    const float* gfW = (const float*)d_in[14];
    const float* gfb = (const float*)d_in[15];
    const float* gaw = (const float*)d_in[16];
    const float* gab = (const float*)d_in[17];
    const float* gbias = (const float*)d_in[18];
    const float* prW = (const float*)d_in[19];
    const float* prb = (const float*)d_in[20];
    const float* dW  = (const float*)d_in[21];
    const float* db  = (const float*)d_in[22];
    const float* dlg = (const float*)d_in[23];
    const float* dlb = (const float*)d_in[24];
    const float* rlg = (const float*)d_in[25];
    const float* rlb = (const float*)d_in[26];
    const float* cW  = (const float*)d_in[27];
    const float* cb  = (const float*)d_in[28];

    // fp32 region
    float* B5     = (float*)d_ws;      // residual sc (fp32)
    float* ssb    = B5 + NHf;          // [N]
    float* tsb    = ssb + N;           // [N]
    float* uvall  = tsb + N;           // [2048]
    float* s0t0a  = uvall + 2048;      // [8]
    float* bcomp  = s0t0a + 8;         // [512]
    float* wuv    = bcomp + 512;       // [512]
    float* wiu    = wuv + 512;         // [256] (+pad to 512)
    float* wuu0   = wiu + 512;         // [512]
    float* cpair1 = wuu0 + 512;        // [4]
    float* cpair0 = cpair1 + 4;        // [4]
    float* wvb    = cpair0 + 4;        // [E]
    int* counts0 = (int*)(wvb + E);
    int* counts1 = counts0 + N;
    int* offs0   = counts1 + N;
    int* offs1   = offs0 + N + 1;
    int* cur0    = offs1 + N + 1;
    int* cur1    = cur0 + N;
    int* tvals   = cur1 + N;           // [E]
    int* eidxb   = tvals + E;          // [E]
    size_t boff = (size_t)((char*)(eidxb + E) - (char*)d_ws);
    boff = (boff + 15) & ~(size_t)15;
    short* HU0   = (short*)((char*)d_ws + boff);  // [NHf]
    short* HI    = HU0 + NHf;
    short* SINEW = HI + NHf;
    short* T4    = SINEW + NHf;
    short* SUF   = T4 + NHf;
    short* ZBUF  = SUF + NHf;
    short* WTu   = ZBUF + NHf;
    short* WTi   = WTu + 512 * 512;
    short* WTg0  = WTi + 512 * 256;
    short* WTg1  = WTg0 + 512 * 512;
    short* WTpr  = WTg1 + 512 * 512;
    short* WTd   = WTpr + 512 * 512;
    short* WuB   = WTd + 4 * 512 * 512;
    short* WTcmp = WuB + 512 * 512;
    short* XB  = SINEW;
    short* ZB  = ZBUF;

    // ---- batched pre-passes ----
    hipLaunchKernelGGL(wtr_all, dim3(16, 16, 10), dim3(32, 8), 0, stream,
                       Wu, Wi, gfW, prW, dW, WTu, WTi, WTg0, WTg1, WTpr, WTd, WuB);
    hipMemsetAsync(counts0, 0, 2 * N * sizeof(int), stream);
    hipLaunchKernelGGL(count2_kernel, dim3((2 * E + 255) / 256), dim3(256), 0, stream,
                       eUI0, eIU1, counts0, counts1, E);
    hipLaunchKernelGGL(scan2_kernel, dim3(2), dim3(1024), 0, stream,
                       counts0, counts1, offs0, offs1, cur0, cur1, N);
    hipLaunchKernelGGL(gat_pre2, dim3(130, 2), dim3(256), 0, stream,
                       gfW, gfb, gaw, uvall, s0t0a);
    hipLaunchKernelGGL(wuvbc2_kernel, dim3(130, 4), dim3(256), 0, stream,
                       Wu, bu, Wi, bi, WTg1, gfb + H, uvall, s0t0a,
                       wuv, cpair1, bcomp, wiu, wuu0, cpair0);
    // composed weight WTcmp = WTg1 x WuB (bf16 512x512)
    hipLaunchKernelGGL(mfma_lin, dim3(16), dim3(256), 0, stream,
                       WTg1, WuB, (const float*)nullptr, (float*)nullptr, WTcmp,
                       512, 512, (const float*)nullptr, (const float*)nullptr,
                       (const short*)nullptr, (const float*)nullptr,
                       (const float*)nullptr, ssb, tsb, 0);

    const int rgrid = (N + 3) / 4;
    const int egrid = (E + 255) / 256;
    const int nwg = ((N + 127) / 128) * 4;

    // ---- combined input transforms + GAT1 rowdot (one big launch) ----
    hipLaunchKernelGGL(mfma_multi, dim3(3 * nwg + rgrid), dim3(256), 0, stream,
                       fu0, WTu, bu, HU0,
                       fi1, WTi, bi, HI,
                       fu2, WTcmp, bcomp, T4,
                       N, fi1, wiu, fu2, wuv, cpair1, ssb, tsb, N);

    // ---- GAT1 ----
    hipLaunchKernelGGL(fill_kernel, dim3(egrid), dim3(256), 0, stream,
                       eIU1, eIU1 + E, ssb, tsb, gab + 1, cur1, tvals, wvb,
                       eidxb, E);
    hipLaunchKernelGGL(gat_agg_kernel, dim3(rgrid), dim3(256), 0, stream,
                       offs1, tvals, wvb, eidxb, T4, HI, gbias + H, SINEW, N);

    // ---- GAT0 (T4 = SINEW@WTg0; mixed rowdot: ss=fu0·wuu0+c, ts=SINEW·v0+t0)
    hipLaunchKernelGGL(mfma_lin, dim3(nwg + rgrid), dim3(256), 0, stream,
                       SINEW, WTg0, gfb, (float*)nullptr, T4, N, 512,
                       fu0, wuu0, SINEW, uvall + 512, cpair0, ssb, tsb, N);
    hipLaunchKernelGGL(fill_kernel, dim3(egrid), dim3(256), 0, stream,
                       eUI0, eUI0 + E, ssb, tsb, gab, cur0, tvals, wvb,
                       eidxb, E);
    hipLaunchKernelGGL(gat_agg_kernel, dim3(rgrid), dim3(256), 0, stream,
                       offs0, tvals, wvb, eidxb, T4, HU0, gbias, SUF, N);

    // Res_DNN head
    hipLaunchKernelGGL(mfma_lin, dim3(nwg), dim3(256), 0, stream,
                       SUF, WTpr, prb, B5, XB, N, 512,
                       (const float*)nullptr, (const float*)nullptr,
                       (const short*)nullptr, (const float*)nullptr,
                       (const float*)nullptr, ssb, tsb, 0);
    for (int r = 0; r < 2; ++r) {
        hipLaunchKernelGGL(mfma_lin, dim3(nwg), dim3(256), 0, stream,
                           XB, WTd + (size_t)(r * 2) * 512 * 512, db + (r * 2) * H,
                           (float*)nullptr, ZB, N, 512,
                           (const float*)nullptr, (const float*)nullptr,
                           (const short*)nullptr, (const float*)nullptr,
                           (const float*)nullptr, ssb, tsb, 0);
        hipLaunchKernelGGL(tanh_ln_kernel, dim3(rgrid), dim3(256), 0, stream,
                           ZB, dlg + (r * 2) * H, dlb + (r * 2) * H, XB, N);
        hipLaunchKernelGGL(mfma_lin, dim3(nwg), dim3(256), 0, stream,
                           XB, WTd + (size_t)(r * 2 + 1) * 512 * 512, db + (r * 2 + 1) * H,
                           (float*)nullptr, ZB, N, 512,
                           (const float*)nullptr, (const float*)nullptr,
                           (const short*)nullptr, (const float*)nullptr,
                           (const float*)nullptr, ssb, tsb, 0);
        if (r == 0) {
            hipLaunchKernelGGL(tanh_ln2_kernel, dim3(rgrid), dim3(256), 0, stream,
                               ZB, B5, dlg + H, dlb + H, rlg, rlb,
                               XB, B5, (const float*)nullptr, (const float*)nullptr,
                               (float*)nullptr, N);
        } else {
            hipLaunchKernelGGL(tanh_ln2_kernel, dim3(rgrid), dim3(256), 0, stream,
                               ZB, B5, dlg + 3 * H, dlb + 3 * H, rlg + H, rlb + H,
                               (short*)nullptr, (float*)nullptr, cW, cb,
                               (float*)d_out, N);
        }
    }
}